// Round 1
// baseline (1092.320 us; speedup 1.0000x reference)
//
#include <hip/hip_runtime.h>
#include <hip/hip_bf16.h>
#include <math.h>

#define C 256
#define C4 (C / 4)      // 64 float4 per row
#define HID 64          // C / R
#define BMAX 32

// ---------------------------------------------------------------------------
// Kernel 1: segment-sum pooling. 64 threads/block (1 wave), each lane owns 4
// channels (float4). Sorted bidx -> register accumulation, atomic flush only
// on segment boundary.
// ---------------------------------------------------------------------------
__global__ __launch_bounds__(64) void pool_kernel(
    const float4* __restrict__ feats4, const int* __restrict__ bidx,
    float* __restrict__ pooled, float* __restrict__ counts,
    int n_rows, int rows_per_block) {
  const int t = threadIdx.x;           // 0..63 -> channels 4t..4t+3
  int start = blockIdx.x * rows_per_block;
  int end = start + rows_per_block;
  if (end > n_rows) end = n_rows;
  if (start >= end) return;

  float4 acc = make_float4(0.f, 0.f, 0.f, 0.f);
  float cnt = 0.f;
  int cur = bidx[start];

  for (int r = start; r < end; ++r) {
    int b = bidx[r];
    if (b != cur) {
      float* dst = pooled + cur * C + t * 4;
      atomicAdd(dst + 0, acc.x);
      atomicAdd(dst + 1, acc.y);
      atomicAdd(dst + 2, acc.z);
      atomicAdd(dst + 3, acc.w);
      if (t == 0) atomicAdd(counts + cur, cnt);
      acc = make_float4(0.f, 0.f, 0.f, 0.f);
      cnt = 0.f;
      cur = b;
    }
    float4 f = feats4[(size_t)r * C4 + t];
    acc.x += f.x; acc.y += f.y; acc.z += f.z; acc.w += f.w;
    cnt += 1.f;
  }
  float* dst = pooled + cur * C + t * 4;
  atomicAdd(dst + 0, acc.x);
  atomicAdd(dst + 1, acc.y);
  atomicAdd(dst + 2, acc.z);
  atomicAdd(dst + 3, acc.w);
  if (t == 0) atomicAdd(counts + cur, cnt);
}

// ---------------------------------------------------------------------------
// Kernel 2: tiny SE-MLP, one block of 256 threads.
// h = relu(mean_pooled @ fc1_w.T + fc1_b)   [B, 64]
// se = sigmoid(h @ fc2_w.T + fc2_b)         [B, 256]
// ---------------------------------------------------------------------------
__global__ __launch_bounds__(256) void mlp_kernel(
    const float* __restrict__ pooled, const float* __restrict__ counts,
    const float* __restrict__ fc1_w, const float* __restrict__ fc1_b,
    const float* __restrict__ fc2_w, const float* __restrict__ fc2_b,
    float* __restrict__ se, int batch) {
  __shared__ float s_pooled[BMAX * C];   // 32 KB
  __shared__ float s_h[BMAX * HID];      // 8 KB
  const int tid = threadIdx.x;

  // mean
  for (int idx = tid; idx < batch * C; idx += 256) {
    int b = idx / C;
    float c = counts[b];
    s_pooled[idx] = pooled[idx] / fmaxf(c, 1.0f);
  }
  __syncthreads();

  // fc1 + relu: 32*64 outputs, dot length 256
  for (int idx = tid; idx < batch * HID; idx += 256) {
    int b = idx / HID, j = idx % HID;
    float d = fc1_b[j];
    const float* pr = s_pooled + b * C;
    const float* wr = fc1_w + j * C;
    #pragma unroll 8
    for (int k = 0; k < C; ++k) d += pr[k] * wr[k];
    s_h[idx] = fmaxf(d, 0.f);
  }
  __syncthreads();

  // fc2 + sigmoid: 32*256 outputs, dot length 64
  for (int idx = tid; idx < batch * C; idx += 256) {
    int b = idx / C, c = idx % C;
    float d = fc2_b[c];
    const float* hr = s_h + b * HID;
    const float* wr = fc2_w + c * HID;
    #pragma unroll 8
    for (int k = 0; k < HID; ++k) d += hr[k] * wr[k];
    se[idx] = 1.0f / (1.0f + expf(-d));
  }
}

// ---------------------------------------------------------------------------
// Kernel 3: out[i] = feats[i] * se[bidx[i]]. One float4 per thread; each
// 64-lane wave maps to exactly one row, so bidx load + se row hit cache.
// ---------------------------------------------------------------------------
__global__ __launch_bounds__(256) void reweight_kernel(
    const float4* __restrict__ feats4, const int* __restrict__ bidx,
    const float4* __restrict__ se4, float4* __restrict__ out4,
    size_t total4) {
  size_t idx = (size_t)blockIdx.x * blockDim.x + threadIdx.x;
  if (idx >= total4) return;
  int row = (int)(idx >> 6);           // /64
  int c4 = (int)(idx & 63);
  int b = bidx[row];
  float4 f = feats4[idx];
  float4 s = se4[(size_t)b * C4 + c4];
  out4[idx] = make_float4(f.x * s.x, f.y * s.y, f.z * s.z, f.w * s.w);
}

extern "C" void kernel_launch(void* const* d_in, const int* in_sizes, int n_in,
                              void* d_out, int out_size, void* d_ws, size_t ws_size,
                              hipStream_t stream) {
  const float* feats = (const float*)d_in[0];
  const float* fc1_w = (const float*)d_in[1];
  const float* fc1_b = (const float*)d_in[2];
  const float* fc2_w = (const float*)d_in[3];
  const float* fc2_b = (const float*)d_in[4];
  const int* bidx = (const int*)d_in[5];
  const int batch = BMAX;  // reference B = 32

  const int n_rows = in_sizes[0] / C;  // 500000

  // workspace layout: pooled[32*256] | counts[32] | se[32*256]
  float* pooled = (float*)d_ws;
  float* counts = pooled + BMAX * C;
  float* se = counts + BMAX;
  hipMemsetAsync(d_ws, 0, (size_t)(BMAX * C + BMAX) * sizeof(float), stream);

  // pool: 8192 blocks * 64 threads -> 32 waves/CU, ~62 rows/block
  const int n_blocks = 8192;
  const int rows_per_block = (n_rows + n_blocks - 1) / n_blocks;
  pool_kernel<<<n_blocks, 64, 0, stream>>>(
      (const float4*)feats, bidx, pooled, counts, n_rows, rows_per_block);

  mlp_kernel<<<1, 256, 0, stream>>>(pooled, counts, fc1_w, fc1_b, fc2_w, fc2_b,
                                    se, batch);

  const size_t total4 = (size_t)n_rows * C4;
  const int rw_blocks = (int)((total4 + 255) / 256);
  reweight_kernel<<<rw_blocks, 256, 0, stream>>>(
      (const float4*)feats, bidx, (const float4*)se, (float4*)d_out, total4);
}